// Round 2
// baseline (408.465 us; speedup 1.0000x reference)
//
#include <hip/hip_runtime.h>

#define IMG_H 256
#define IMG_W 256
#define IMG_C 3
#define KS 33
#define PAD 16
#define THRESH 1e-4f
#define FH_PER 3          // 33 fh values in 11 chunks of 3
#define ROWS_PER_BLK 4    // 4 image rows per block, 4 px per thread
#define PADW (IMG_W + 2 * PAD)   // 288: replication-padded row width
#define NROWS (IMG_C * (ROWS_PER_BLK + FH_PER - 1))  // 3 ch * 6 rows = 18

// Block: 256 threads. Thread t: row r = t>>6 within block, handles 4 px at x4 = (t&63)*4.
// Grid: (64 row-quads, 11 fh-chunks). Kernels read as float4 (16 B/lane, peak-BW pattern).
// Image rows staged in LDS with replication padding baked in; inner loop uses an
// aligned ds_read_b128 sliding window (all component indices compile-time).
__global__ __launch_bounds__(256, 4)
void reblur_kernel(const float* __restrict__ img,
                   const float* __restrict__ ker,
                   float* __restrict__ out)
{
    __shared__ float lds[NROWS * PADW];   // 18*288*4 = 20736 B

    const int tid = threadIdx.x;
    const int y0 = blockIdx.x * ROWS_PER_BLK;   // first image row of this block
    const int fh0 = blockIdx.y * FH_PER;        // first filter row of this chunk
    const int plane = IMG_H * IMG_W;

    // ---- Stage 18 replication-padded rows (6 window rows x 3 channels) ----
    const int ybase = y0 + fh0 - PAD;           // image row of window row 0
    #pragma unroll
    for (int ch = 0; ch < IMG_C; ++ch) {
        #pragma unroll
        for (int rw = 0; rw < ROWS_PER_BLK + FH_PER - 1; ++rw) {
            int yy = ybase + rw;
            yy = yy < 0 ? 0 : (yy > IMG_H - 1 ? IMG_H - 1 : yy);
            const float* __restrict__ src = img + ch * plane + yy * IMG_W;
            float* dst = lds + (ch * (ROWS_PER_BLK + FH_PER - 1) + rw) * PADW;
            for (int p = tid; p < PADW; p += 256) {
                int sc = p - PAD;
                sc = sc < 0 ? 0 : (sc > IMG_W - 1 ? IMG_W - 1 : sc);
                dst[p] = src[sc];
            }
        }
    }
    __syncthreads();

    // ---- Compute: 4 px per thread, float4 kernel-weight loads ----
    const int r = tid >> 6;          // 0..3 : row within block
    const int l = tid & 63;          // lane
    const int x4 = l << 2;           // 0..252 : first pixel x
    const int y = y0 + r;

    const float4* __restrict__ ker4 = (const float4*)ker;
    // float4 index for tap t (t = dfh*33+fw): (fh0*33 + t)*16384 + y*64 + l
    const size_t kbase = (size_t)(fh0 * KS) * (plane / 4) + (size_t)y * (IMG_W / 4) + l;

    float acc[IMG_C][4];
    #pragma unroll
    for (int c = 0; c < IMG_C; ++c)
        #pragma unroll
        for (int p = 0; p < 4; ++p) acc[c][p] = 0.f;

    #pragma unroll
    for (int dfh = 0; dfh < FH_PER; ++dfh) {
        // Sliding window: win[ch][0..3] covers padded cols [x4+4g .. x4+4g+3],
        // win[ch][4..7] the next 4. All accesses below have literal indices.
        float win[IMG_C][8];
        int woff[IMG_C];
        #pragma unroll
        for (int c = 0; c < IMG_C; ++c) {
            woff[c] = (c * (ROWS_PER_BLK + FH_PER - 1) + r + dfh) * PADW + x4;
            float4 t0 = *(const float4*)&lds[woff[c]];
            win[c][0] = t0.x; win[c][1] = t0.y; win[c][2] = t0.z; win[c][3] = t0.w;
        }
        const size_t kb = kbase + (size_t)(dfh * KS) * (plane / 4);

        #pragma unroll
        for (int g = 0; g < 8; ++g) {       // fw groups of 4: fw = 4g+j
            #pragma unroll
            for (int c = 0; c < IMG_C; ++c) {
                float4 t1 = *(const float4*)&lds[woff[c] + 4 * (g + 1)];
                win[c][4] = t1.x; win[c][5] = t1.y; win[c][6] = t1.z; win[c][7] = t1.w;
            }
            #pragma unroll
            for (int j = 0; j < 4; ++j) {
                const int fw = 4 * g + j;
                float4 kw = ker4[kb + (size_t)fw * (plane / 4)];
                float w0 = kw.x > THRESH ? kw.x : 0.f;
                float w1 = kw.y > THRESH ? kw.y : 0.f;
                float w2 = kw.z > THRESH ? kw.z : 0.f;
                float w3 = kw.w > THRESH ? kw.w : 0.f;
                #pragma unroll
                for (int c = 0; c < IMG_C; ++c) {
                    acc[c][0] = fmaf(w0, win[c][j + 0], acc[c][0]);
                    acc[c][1] = fmaf(w1, win[c][j + 1], acc[c][1]);
                    acc[c][2] = fmaf(w2, win[c][j + 2], acc[c][2]);
                    acc[c][3] = fmaf(w3, win[c][j + 3], acc[c][3]);
                }
            }
            // rotate window
            #pragma unroll
            for (int c = 0; c < IMG_C; ++c) {
                win[c][0] = win[c][4]; win[c][1] = win[c][5];
                win[c][2] = win[c][6]; win[c][3] = win[c][7];
            }
        }
        {   // fw = 32 epilogue: window [32..35] is current win[c][0..3]
            float4 kw = ker4[kb + (size_t)32 * (plane / 4)];
            float w0 = kw.x > THRESH ? kw.x : 0.f;
            float w1 = kw.y > THRESH ? kw.y : 0.f;
            float w2 = kw.z > THRESH ? kw.z : 0.f;
            float w3 = kw.w > THRESH ? kw.w : 0.f;
            #pragma unroll
            for (int c = 0; c < IMG_C; ++c) {
                acc[c][0] = fmaf(w0, win[c][0], acc[c][0]);
                acc[c][1] = fmaf(w1, win[c][1], acc[c][1]);
                acc[c][2] = fmaf(w2, win[c][2], acc[c][2]);
                acc[c][3] = fmaf(w3, win[c][3], acc[c][3]);
            }
        }
    }

    // ---- Accumulate into out (zeroed by memset; 11 chunks collide per addr) ----
    float* op = out + y * IMG_W + x4;
    #pragma unroll
    for (int c = 0; c < IMG_C; ++c) {
        #pragma unroll
        for (int p = 0; p < 4; ++p)
            atomicAdd(op + c * plane + p, acc[c][p]);
    }
}

extern "C" void kernel_launch(void* const* d_in, const int* in_sizes, int n_in,
                              void* d_out, int out_size, void* d_ws, size_t ws_size,
                              hipStream_t stream) {
    const float* img = (const float*)d_in[0];   // [1,3,256,256] fp32
    const float* ker = (const float*)d_in[1];   // [1,1089,256,256] fp32
    float* out = (float*)d_out;                 // [1,3,256,256] fp32

    hipMemsetAsync(out, 0, (size_t)out_size * sizeof(float), stream);

    dim3 grid(IMG_H / ROWS_PER_BLK, KS / FH_PER);   // (64, 11)
    reblur_kernel<<<grid, 256, 0, stream>>>(img, ker, out);
}